// Round 1
// baseline (24525.697 us; speedup 1.0000x reference)
//
#include <hip/hip_runtime.h>
#include <hip/hip_cooperative_groups.h>

namespace cg = cooperative_groups;

using short8 = __attribute__((ext_vector_type(8))) short;
using f32x4  = __attribute__((ext_vector_type(4))) float;

// ---------------- workspace layout (bytes) ----------------
static constexpr size_t N_W0   = (size_t)2 * 2048 * 576;    // layer0 cat-weights bf16 (x padded 16->64, then h 512)
static constexpr size_t N_W123 = (size_t)6 * 2048 * 1536;   // layers 1..3 cat-weights bf16
static constexpr size_t N_BS   = (size_t)8 * 2048;          // bias sums fp32 [l*2+d][2048]
static constexpr size_t N_XP   = (size_t)128 * 256 * 64;    // padded embedded input bf16 [t][b][64]
static constexpr size_t N_XC   = (size_t)2 * 4 * 256 * 1024;// h (bf16) double-buffered by t-parity: [par][l][b][d*512+j]
static constexpr size_t N_C    = (size_t)8 * 256 * 512;     // c fp32 [l*2+d][b][j]
static constexpr size_t N_FCT  = (size_t)8192 * 64;         // fc_w transposed fp32 [k][o]

static constexpr size_t OFF_W0   = 0;
static constexpr size_t OFF_W123 = OFF_W0 + N_W0 * 2;
static constexpr size_t OFF_BS   = OFF_W123 + N_W123 * 2;
static constexpr size_t OFF_XP   = OFF_BS + N_BS * 4;
static constexpr size_t OFF_XC   = OFF_XP + N_XP * 2;
static constexpr size_t OFF_C    = OFF_XC + N_XC * 2;
static constexpr size_t OFF_H    = OFF_C + N_C * 4;         // h fp32, same layout as c
static constexpr size_t OFF_FCT  = OFF_H + N_C * 4;
static constexpr size_t WS_NEEDED = OFF_FCT + N_FCT * 4;    // ~61.4 MB

__device__ __forceinline__ short f2bf(float f) {
  unsigned u = __float_as_uint(f);
  u += 0x7fff + ((u >> 16) & 1);   // round-to-nearest-even
  return (short)(u >> 16);
}

// ---------------- prep kernels (run once per call) ----------------
__global__ void k_prep_w0(const float* __restrict__ Wih0, const float* __restrict__ Whh0,
                          short* __restrict__ W0b) {
  int idx = blockIdx.x * blockDim.x + threadIdx.x;
  if (idx >= (int)N_W0) return;
  int k = idx % 576;
  int g = (idx / 576) % 2048;
  int d = idx / (576 * 2048);
  float v = 0.f;
  if (k < 64) { if (k < 16) v = Wih0[(d * 2048 + g) * 16 + k]; }
  else v = Whh0[(d * 2048 + g) * 512 + (k - 64)];
  W0b[idx] = f2bf(v);
}

__global__ void k_prep_w123(const float* __restrict__ Wih, const float* __restrict__ Whh,
                            short* __restrict__ W123b) {
  int idx = blockIdx.x * blockDim.x + threadIdx.x;
  if (idx >= (int)N_W123) return;
  int k = idx % 1536;
  int g = (idx / 1536) % 2048;
  int ld = idx / (1536 * 2048);   // (l-1)*2 + d, 0..5
  float v;
  if (k < 1024) v = Wih[((size_t)ld * 2048 + g) * 1024 + k];
  else          v = Whh[((size_t)ld * 2048 + g) * 512 + (k - 1024)];
  W123b[idx] = f2bf(v);
}

__global__ void k_prep_bias(const float* __restrict__ bih0, const float* __restrict__ bhh0,
                            const float* __restrict__ bih, const float* __restrict__ bhh,
                            float* __restrict__ bsum) {
  int idx = blockIdx.x * blockDim.x + threadIdx.x;
  if (idx >= (int)N_BS) return;
  int g = idx & 2047;
  int d = (idx >> 11) & 1;
  int l = idx >> 12;
  float v;
  if (l == 0) v = bih0[d * 2048 + g] + bhh0[d * 2048 + g];
  else        v = bih[((l - 1) * 2 + d) * 2048 + g] + bhh[((l - 1) * 2 + d) * 2048 + g];
  bsum[idx] = v;
}

__global__ void k_prep_xp(const int* __restrict__ tok, const float* __restrict__ embed,
                          short* __restrict__ XP) {
  int idx = blockIdx.x * blockDim.x + threadIdx.x;
  if (idx >= (int)N_XP) return;
  int k = idx & 63;
  int tb = idx >> 6;               // t*256 + b
  float v = 0.f;
  if (k < 16) v = embed[tok[tb] * 16 + k];
  XP[idx] = f2bf(v);
}

__global__ void k_prep_fcT(const float* __restrict__ fc_w, float* __restrict__ fcT) {
  int idx = blockIdx.x * blockDim.x + threadIdx.x;
  if (idx >= (int)N_FCT) return;
  int o = idx & 63;
  int k = idx >> 6;
  fcT[idx] = fc_w[o * 8192 + k];   // fcT[k][o]
}

// ---------------- main recurrent kernel (cooperative) ----------------
// grid = 256 blocks x 256 threads; block -> (d = blk>>7, bc = (blk>>5)&3, jc = blk&31)
// tile: 64 batch rows x 16 h-cols, N-cols are 4 gate strips (g = gt*512 + jc*16 + jj)
__global__ void __launch_bounds__(256, 1)
k_lstm(const short* __restrict__ W0b, const short* __restrict__ W123b,
       const float* __restrict__ bsum, const short* __restrict__ XP,
       short* __restrict__ xc, float* __restrict__ cb, float* __restrict__ hf) {
  cg::grid_group grid = cg::this_grid();
  const int blk = blockIdx.x;
  const int d  = blk >> 7;
  const int bc = (blk >> 5) & 3;
  const int jc = blk & 31;
  const int tid = threadIdx.x;
  const int w = tid >> 6;          // wave 0..3 -> m-rows w*16..w*16+15
  const int lane = tid & 63;
  const int q = lane >> 4;
  const int lr = lane & 15;

  __shared__ short As[64][72];     // 64 rows x 64 k, +8 bf16 pad (16B) to break bank stride
  __shared__ short Bs[64][72];

  for (int t = 0; t < 128; ++t) {
    const int parW = t & 1;        // parity written this timestep
    const int parR = parW ^ 1;     // parity holding t-1's h
    for (int l = 0; l < 4; ++l) {
      const int K = (l == 0) ? 576 : 1536;
      const int xlen = (l == 0) ? 64 : 1024;
      const short* Wp = (l == 0) ? (W0b + d * (2048 * 576))
                                 : (W123b + (size_t)((l - 1) * 2 + d) * (2048 * 1536));
      const short* xprev = (l == 0) ? (XP + t * (256 * 64))
                                    : (xc + (parW * 4 + (l - 1)) * (256 * 1024));
      const int xrow = (l == 0) ? 64 : 1024;
      const short* xself = xc + (parR * 4 + l) * (256 * 1024);

      f32x4 acc0, acc1, acc2, acc3;
      #pragma unroll
      for (int e = 0; e < 4; ++e) { acc0[e] = 0.f; acc1[e] = 0.f; acc2[e] = 0.f; acc3[e] = 0.f; }

      for (int k0 = 0; k0 < K; k0 += 64) {
        // ---- stage A (x_cat rows) and B (weight rows, B^T layout) into LDS ----
        #pragma unroll
        for (int c = 0; c < 2; ++c) {
          int chunk = tid + c * 256;           // 0..511 chunks of 8 bf16
          int r  = chunk >> 3;                 // row 0..63
          int ko = (chunk & 7) * 8;            // k-offset 0..56
          int kg = k0 + ko;
          int b = bc * 64 + r;
          const short* asrc = (kg < xlen) ? (xprev + b * xrow + kg)
                                          : (xself + b * 1024 + d * 512 + (kg - xlen));
          *(short8*)&As[r][ko] = *(const short8*)asrc;
          int g = ((r >> 4) << 9) + (jc << 4) + (r & 15);   // gate strip mapping
          *(short8*)&Bs[r][ko] = *(const short8*)(Wp + (size_t)g * K + kg);
        }
        __syncthreads();
        // ---- MFMA: wave w does 16(m) x 64(n=4 gate strips) for this 64-k slab ----
        #pragma unroll
        for (int ks = 0; ks < 64; ks += 32) {
          short8 a  = *(const short8*)&As[w * 16 + lr][ks + q * 8];
          short8 b0 = *(const short8*)&Bs[ 0 + lr][ks + q * 8];
          short8 b1 = *(const short8*)&Bs[16 + lr][ks + q * 8];
          short8 b2 = *(const short8*)&Bs[32 + lr][ks + q * 8];
          short8 b3 = *(const short8*)&Bs[48 + lr][ks + q * 8];
          acc0 = __builtin_amdgcn_mfma_f32_16x16x32_bf16(a, b0, acc0, 0, 0, 0);
          acc1 = __builtin_amdgcn_mfma_f32_16x16x32_bf16(a, b1, acc1, 0, 0, 0);
          acc2 = __builtin_amdgcn_mfma_f32_16x16x32_bf16(a, b2, acc2, 0, 0, 0);
          acc3 = __builtin_amdgcn_mfma_f32_16x16x32_bf16(a, b3, acc3, 0, 0, 0);
        }
        __syncthreads();
      }

      // ---- fused LSTM cell epilogue: lane holds rows q*4+r, col lr of each gate ----
      const int s = l * 2 + d;
      const int j = (jc << 4) + lr;
      const float* bsl = bsum + s * 2048;
      const float b_i = bsl[j], b_f = bsl[512 + j], b_g = bsl[1024 + j], b_o = bsl[1536 + j];
      const int bbase = bc * 64 + w * 16 + q * 4;
      short* xcw = xc + (parW * 4 + l) * (256 * 1024);
      #pragma unroll
      for (int r = 0; r < 4; ++r) {
        int b = bbase + r;
        size_t cidx = ((size_t)s * 256 + b) * 512 + j;
        float gi = acc0[r] + b_i;
        float gf = acc1[r] + b_f;
        float gg = acc2[r] + b_g;
        float go = acc3[r] + b_o;
        float si = 1.f / (1.f + __expf(-gi));
        float sf = 1.f / (1.f + __expf(-gf));
        float so = 1.f / (1.f + __expf(-go));
        float cn = sf * cb[cidx] + si * tanhf(gg);
        float hn = so * tanhf(cn);
        cb[cidx] = cn;
        hf[cidx] = hn;
        xcw[b * 1024 + d * 512 + j] = f2bf(hn);
      }
      grid.sync();
    }
  }
}

// ---------------- final FC + softmax ----------------
// grid = 64 blocks x 256 threads; block -> 4 batch rows, wave q -> row blk*4+q, lane -> output o
__global__ void __launch_bounds__(256)
k_fc(const float* __restrict__ hf, const float* __restrict__ cb,
     const float* __restrict__ fcT, const float* __restrict__ fc_b,
     float* __restrict__ out) {
  const int tid = threadIdx.x;
  const int o = tid & 63;
  const int q = tid >> 6;
  const int bi = blockIdx.x * 4 + q;
  __shared__ float hidc[4][128];
  float acc = 0.f;
  for (int k0 = 0; k0 < 8192; k0 += 128) {
    #pragma unroll
    for (int c = 0; c < 2; ++c) {
      int idx = tid + c * 256;                 // 0..511
      int r = idx >> 7, kk = idx & 127;
      int k = k0 + kk;
      int s = k >> 10, rem = k & 1023, part = rem >> 9, j = rem & 511;
      const float* src = part ? cb : hf;       // hid = [h | c] per (l,d) slice
      hidc[r][kk] = src[((size_t)s * 256 + (blockIdx.x * 4 + r)) * 512 + j];
    }
    __syncthreads();
    const float* hrow = hidc[q];
    #pragma unroll 8
    for (int kk = 0; kk < 128; ++kk)
      acc += hrow[kk] * fcT[(k0 + kk) * 64 + o];
    __syncthreads();
  }
  float v = acc + fc_b[o];
  float m = v;
  #pragma unroll
  for (int off = 32; off; off >>= 1) m = fmaxf(m, __shfl_xor(m, off, 64));
  float e = __expf(v - m);
  float ssum = e;
  #pragma unroll
  for (int off = 32; off; off >>= 1) ssum += __shfl_xor(ssum, off, 64);
  out[bi * 64 + o] = e / ssum;
}

// ---------------- launcher ----------------
extern "C" void kernel_launch(void* const* d_in, const int* in_sizes, int n_in,
                              void* d_out, int out_size, void* d_ws, size_t ws_size,
                              hipStream_t stream) {
  const int*   tok   = (const int*)d_in[0];
  const float* embed = (const float*)d_in[1];
  const float* Wih0  = (const float*)d_in[2];
  const float* Whh0  = (const float*)d_in[3];
  const float* bih0  = (const float*)d_in[4];
  const float* bhh0  = (const float*)d_in[5];
  const float* Wih   = (const float*)d_in[6];
  const float* Whh   = (const float*)d_in[7];
  const float* bih   = (const float*)d_in[8];
  const float* bhh   = (const float*)d_in[9];
  const float* fc_w  = (const float*)d_in[10];
  const float* fc_b  = (const float*)d_in[11];
  float* out = (float*)d_out;

  if (ws_size < WS_NEEDED) return;   // workspace too small: fail visibly (poison stays)

  char* ws = (char*)d_ws;
  short* W0b   = (short*)(ws + OFF_W0);
  short* W123b = (short*)(ws + OFF_W123);
  float* bsum  = (float*)(ws + OFF_BS);
  short* XP    = (short*)(ws + OFF_XP);
  short* xc    = (short*)(ws + OFF_XC);
  float* cbuf  = (float*)(ws + OFF_C);
  float* hfbuf = (float*)(ws + OFF_H);
  float* fcT   = (float*)(ws + OFF_FCT);

  // zero initial state: parity-1 h buffer (read as h_{t=-1}) and all of c
  hipMemsetAsync(ws + OFF_XC + (size_t)4 * 256 * 1024 * 2, 0, (size_t)4 * 256 * 1024 * 2, stream);
  hipMemsetAsync(ws + OFF_C, 0, N_C * 4, stream);

  k_prep_w0  <<<(N_W0   + 255) / 256, 256, 0, stream>>>(Wih0, Whh0, W0b);
  k_prep_w123<<<(N_W123 + 255) / 256, 256, 0, stream>>>(Wih, Whh, W123b);
  k_prep_bias<<<(N_BS   + 255) / 256, 256, 0, stream>>>(bih0, bhh0, bih, bhh, bsum);
  k_prep_xp  <<<(N_XP   + 255) / 256, 256, 0, stream>>>(tok, embed, XP);
  k_prep_fcT <<<(N_FCT  + 255) / 256, 256, 0, stream>>>(fc_w, fcT);

  void* kargs[] = {(void*)&W0b, (void*)&W123b, (void*)&bsum, (void*)&XP,
                   (void*)&xc, (void*)&cbuf, (void*)&hfbuf};
  hipLaunchCooperativeKernel((void*)k_lstm, dim3(256), dim3(256), kargs, 0, stream);

  k_fc<<<64, 256, 0, stream>>>(hfbuf, cbuf, fcT, fc_b, out);
}

// Round 2
// 6961.220 us; speedup vs baseline: 3.5232x; 3.5232x over previous
//
#include <hip/hip_runtime.h>
#include <hip/hip_cooperative_groups.h>

namespace cg = cooperative_groups;

using short8 = __attribute__((ext_vector_type(8))) short;
using f32x4  = __attribute__((ext_vector_type(4))) float;
using f32x2  = __attribute__((ext_vector_type(2))) float;

// ---------------- workspace layout ----------------
// Weight fragments (bf16), laid out so each wave's register load is coalesced b128:
//   l0:   [d][nc][wv][sl(3)][gt][lane*8+j]   (K padded to 768; k>=576 zero)
//   l123: [ldm][nc][wv][sl(6)][gt][lane*8+j] (K=1536)
static constexpr size_t N_WF0 = (size_t)2*32*8*3*4*512;   // shorts
static constexpr size_t N_WF1 = (size_t)6*32*8*6*4*512;   // shorts
static constexpr size_t N_WF  = N_WF0 + N_WF1;
static constexpr size_t N_BSE = (size_t)8*2048;           // f32 bias sums
static constexpr size_t N_XPE = (size_t)128*2*256*8;      // shorts, embed k8-major [t][kg2][b][8]
static constexpr size_t N_HBE = (size_t)2*8*64*256*8;     // shorts, h dbuf [par][ld][kgrp][b][8]
static constexpr size_t N_CBE = (size_t)8*256*512;        // f32 c state [ld][b][j]
static constexpr size_t N_FCT = (size_t)8192*64;          // f32 fc_w^T [k][o]

static constexpr size_t OFF_WF = 0;
static constexpr size_t OFF_BS = OFF_WF + N_WF*2;
static constexpr size_t OFF_XP = OFF_BS + N_BSE*4;
static constexpr size_t OFF_HB = OFF_XP + N_XPE*2;
static constexpr size_t OFF_CB = OFF_HB + N_HBE*2;
static constexpr size_t OFF_HF = OFF_CB + N_CBE*4;
static constexpr size_t OFF_FC = OFF_HF + N_CBE*4;
static constexpr size_t WS_NEEDED = OFF_FC + N_FCT*4;     // ~59.8 MB

__device__ __forceinline__ short f2bf(float f) {
  unsigned u = __float_as_uint(f);
  u += 0x7fff + ((u >> 16) & 1);   // RNE
  return (short)(u >> 16);
}

// ---------------- prep kernels ----------------
__global__ void k_prep_wf(const float* __restrict__ Wih0, const float* __restrict__ Whh0,
                          const float* __restrict__ Wih,  const float* __restrict__ Whh,
                          short* __restrict__ Wf) {
  size_t idx = (size_t)blockIdx.x * blockDim.x + threadIdx.x;
  if (idx >= N_WF) return;
  int j  = (int)(idx & 7);
  int lane = (int)((idx >> 3) & 63);
  int gt = (int)((idx >> 9) & 3);
  int lr = lane & 15, qq = lane >> 4;
  float v;
  if (idx < N_WF0) {
    size_t rest = idx >> 11;
    int sl = (int)(rest % 3); size_t r2 = rest / 3;
    int wvv = (int)(r2 & 7);  size_t r3 = r2 >> 3;
    int ncc = (int)(r3 & 31); int dd = (int)(r3 >> 5);
    int g = gt*512 + ncc*16 + lr;
    int k = (wvv*3 + sl)*32 + qq*8 + j;           // 0..767
    if (k < 16)       v = Wih0[((size_t)dd*2048 + g)*16 + k];
    else if (k < 64)  v = 0.f;
    else if (k < 576) v = Whh0[((size_t)dd*2048 + g)*512 + (k - 64)];
    else              v = 0.f;
  } else {
    size_t u = idx - N_WF0;
    size_t rest = u >> 11;
    int sl = (int)(rest % 6); size_t r2 = rest / 6;
    int wvv = (int)(r2 & 7);  size_t r3 = r2 >> 3;
    int ncc = (int)(r3 & 31); int ldm = (int)(r3 >> 5);   // (l-1)*2+d
    int g = gt*512 + ncc*16 + lr;
    int k = (wvv*6 + sl)*32 + qq*8 + j;           // 0..1535
    if (k < 1024) v = Wih[((size_t)ldm*2048 + g)*1024 + k];
    else          v = Whh[((size_t)ldm*2048 + g)*512 + (k - 1024)];
  }
  Wf[idx] = f2bf(v);
}

__global__ void k_prep_bias(const float* __restrict__ bih0, const float* __restrict__ bhh0,
                            const float* __restrict__ bih, const float* __restrict__ bhh,
                            float* __restrict__ bsum) {
  int idx = blockIdx.x * blockDim.x + threadIdx.x;
  if (idx >= (int)N_BSE) return;
  int g = idx & 2047;
  int dd = (idx >> 11) & 1;
  int ll = idx >> 12;
  float v;
  if (ll == 0) v = bih0[dd*2048 + g] + bhh0[dd*2048 + g];
  else         v = bih[((ll-1)*2 + dd)*2048 + g] + bhh[((ll-1)*2 + dd)*2048 + g];
  bsum[idx] = v;
}

__global__ void k_prep_xp(const int* __restrict__ tok, const float* __restrict__ embed,
                          short* __restrict__ XP) {
  int idx = blockIdx.x * blockDim.x + threadIdx.x;
  if (idx >= (int)N_XPE) return;
  int i  = idx & 7;
  int b  = (idx >> 3) & 255;
  int kg = (idx >> 11) & 1;
  int t  = idx >> 12;
  int k = kg*8 + i;                                // 0..15
  XP[idx] = f2bf(embed[tok[t*256 + b]*16 + k]);
}

__global__ void k_prep_fcT(const float* __restrict__ fc_w, float* __restrict__ fcT) {
  int idx = blockIdx.x * blockDim.x + threadIdx.x;
  if (idx >= (int)N_FCT) return;
  int o = idx & 63;
  int k = idx >> 6;
  fcT[idx] = fc_w[o * 8192 + k];
}

// ---------------- main recurrent kernel ----------------
// 256 blocks x 512 threads, cooperative. block = (ld = blk&7, nc = blk>>3).
// Wavefront over diagonal s: layer l works on t = s - l. 131 grid syncs total.
// 8 waves split K 8 ways; weights live in 96 VGPRs/lane for the whole kernel.
__global__ void __launch_bounds__(512, 2)
k_lstm(const short* __restrict__ Wf, const float* __restrict__ bsum,
       const short* __restrict__ XP, short* __restrict__ hb,
       float* __restrict__ cb, float* __restrict__ hf) {
  cg::grid_group grid = cg::this_grid();
  const int blk = blockIdx.x;
  const int ld = blk & 7, nc = blk >> 3;
  const int l = ld >> 1, d = ld & 1;
  const int tid = threadIdx.x;
  const int wv = tid >> 6, lane = tid & 63;
  const int q = lane >> 4, lr = lane & 15;
  const int SLb = (l == 0) ? 3 : 6;
  const size_t HB_LD = 131072;   // shorts per (par,ld) h-buffer

  __shared__ float red[2][8][4][16][16];   // [mt-in-pair][wv][gt][n][m] = 64 KB

  // epilogue thread statics (threads 0..255 do the cell update)
  const int eu  = tid >> 7;        // mt within pair
  const int en  = (tid >> 3) & 15; // n col
  const int emh = tid & 7;         // m half-quad (m = emh*2 + e)
  float bias4[4];
  if (tid < 256) {
    #pragma unroll
    for (int gt = 0; gt < 4; ++gt)
      bias4[gt] = bsum[ld*2048 + gt*512 + nc*16 + en];
  }

  // ---- load this wave's weight slice into registers (persist across all 131 steps) ----
  short8 wreg[6][4];
  {
    const short* wb = (l == 0)
      ? (Wf + (size_t)(d*32 + nc) * (8*3*4*512) + (size_t)wv * (3*4*512))
      : (Wf + N_WF0 + (size_t)((ld - 2)*32 + nc) * (8*6*4*512) + (size_t)wv * (6*4*512));
    #pragma unroll
    for (int sl = 0; sl < 6; ++sl) {
      #pragma unroll
      for (int gt = 0; gt < 4; ++gt) {
        if (sl < SLb) wreg[sl][gt] = *(const short8*)(wb + (sl*4 + gt)*512 + lane*8);
        else          wreg[sl][gt] = short8{0,0,0,0,0,0,0,0};
      }
    }
  }

  float* cbl = cb + (size_t)ld * (256*512);

  for (int s = 0; s < 131; ++s) {
    const int t = s - l;
    if (t >= 0 && t < 128) {
      const int pt = t & 1, pm = pt ^ 1;
      // per-slab lane-adjusted A pointers (k8-major sources)
      const short* apl[6];
      #pragma unroll
      for (int sl = 0; sl < 6; ++sl) {
        int S = wv * SLb + sl;
        const short* p; int lo;
        if (l == 0) {
          if (S < 2) { p = XP + (size_t)t * 4096; lo = (q < 1 ? q : 1) * 2048 + lr * 8; }
          else {
            int klb = (S <= 17) ? (4*S - 8) : 0;   // S>17: zero weights, any valid addr
            p = hb + (size_t)(pm*8 + ld) * HB_LD + (size_t)klb * 2048;
            lo = q * 2048 + lr * 8;
          }
        } else {
          const int pl0 = ld - 2 - d;              // (l-1)*2
          if (S < 16)      p = hb + (size_t)(pt*8 + pl0    ) * HB_LD + (size_t)(4*S      ) * 2048;
          else if (S < 32) p = hb + (size_t)(pt*8 + pl0 + 1) * HB_LD + (size_t)(4*S - 64 ) * 2048;
          else             p = hb + (size_t)(pm*8 + ld     ) * HB_LD + (size_t)(4*S - 128) * 2048;
          lo = q * 2048 + lr * 8;
        }
        apl[sl] = p + lo;
      }

      // prime A for round 0
      short8 a[6][2];
      #pragma unroll
      for (int sl = 0; sl < 6; ++sl)
        if (sl < SLb) {
          a[sl][0] = *(const short8*)(apl[sl]);
          a[sl][1] = *(const short8*)(apl[sl] + 128);
        }

      for (int ro = 0; ro < 8; ++ro) {   // 8 rounds x 2 m-tiles = 256 batch rows
        // early c preload for the epilogue (latency hidden by MFMA loop)
        float c0 = 0.f, c1 = 0.f; int b0 = 0, b1 = 0, ej = 0;
        if (tid < 256) {
          ej = nc*16 + en;
          b0 = (ro*2 + eu)*16 + emh*2;
          b1 = b0 + 1;
          c0 = cbl[(size_t)b0*512 + ej];
          c1 = cbl[(size_t)b1*512 + ej];
        }
        f32x4 acc[2][4];
        #pragma unroll
        for (int u = 0; u < 2; ++u)
          #pragma unroll
          for (int gt = 0; gt < 4; ++gt) acc[u][gt] = f32x4{0.f,0.f,0.f,0.f};
        #pragma unroll
        for (int sl = 0; sl < 6; ++sl)
          if (sl < SLb) {
            #pragma unroll
            for (int gt = 0; gt < 4; ++gt) {
              acc[0][gt] = __builtin_amdgcn_mfma_f32_16x16x32_bf16(a[sl][0], wreg[sl][gt], acc[0][gt], 0,0,0);
              acc[1][gt] = __builtin_amdgcn_mfma_f32_16x16x32_bf16(a[sl][1], wreg[sl][gt], acc[1][gt], 0,0,0);
            }
          }
        // prefetch next round's A (latency spans the reduction/epilogue)
        if (ro < 7) {
          const int mo = (ro + 1) * 256;
          #pragma unroll
          for (int sl = 0; sl < 6; ++sl)
            if (sl < SLb) {
              a[sl][0] = *(const short8*)(apl[sl] + mo);
              a[sl][1] = *(const short8*)(apl[sl] + mo + 128);
            }
        }
        // packed b128 partial writes: red[u][wv][gt][n=lr][m=q*4+r]
        #pragma unroll
        for (int u = 0; u < 2; ++u)
          #pragma unroll
          for (int gt = 0; gt < 4; ++gt)
            *(f32x4*)&red[u][wv][gt][lr][q*4] = acc[u][gt];
        __syncthreads();
        if (tid < 256) {
          float g2[4][2];
          #pragma unroll
          for (int gt = 0; gt < 4; ++gt) {
            f32x2 sum = f32x2{0.f, 0.f};
            #pragma unroll
            for (int w8 = 0; w8 < 8; ++w8)
              sum += *(const f32x2*)&red[eu][w8][gt][en][emh*2];
            g2[gt][0] = sum[0] + bias4[gt];
            g2[gt][1] = sum[1] + bias4[gt];
          }
          short* hw = hb + (size_t)(pt*8 + ld) * HB_LD;
          #pragma unroll
          for (int e = 0; e < 2; ++e) {
            float gi = g2[0][e], gf = g2[1][e], gg = g2[2][e], go = g2[3][e];
            float si = 1.f/(1.f + __expf(-gi));
            float sf = 1.f/(1.f + __expf(-gf));
            float so = 1.f/(1.f + __expf(-go));
            float tg = 1.f - 2.f/(1.f + __expf(2.f*gg));
            float cold = e ? c1 : c0;
            int   b    = e ? b1 : b0;
            float cn = sf * cold + si * tg;
            float tc = 1.f - 2.f/(1.f + __expf(2.f*cn));
            float hn = so * tc;
            cbl[(size_t)b*512 + ej] = cn;
            hw[((size_t)(ej >> 3) * 256 + b) * 8 + (ej & 7)] = f2bf(hn);
            if (t == 127) hf[((size_t)ld*256 + b)*512 + ej] = hn;
          }
        }
        __syncthreads();
      }
    }
    grid.sync();
  }
}

// ---------------- final FC + softmax ----------------
__global__ void __launch_bounds__(256)
k_fc(const float* __restrict__ hf, const float* __restrict__ cb,
     const float* __restrict__ fcT, const float* __restrict__ fc_b,
     float* __restrict__ out) {
  const int tid = threadIdx.x;
  const int o = tid & 63;
  const int qw = tid >> 6;
  const int bi = blockIdx.x * 4 + qw;
  __shared__ float hidc[4][128];
  float acc = 0.f;
  for (int k0 = 0; k0 < 8192; k0 += 128) {
    #pragma unroll
    for (int c = 0; c < 2; ++c) {
      int idx = tid + c * 256;                 // 0..511
      int r = idx >> 7, kk = idx & 127;
      int k = k0 + kk;
      int sS = k >> 10, rem = k & 1023, part = rem >> 9, j = rem & 511;
      const float* src = part ? cb : hf;       // hid = [h | c] per (l,d) slice
      hidc[r][kk] = src[((size_t)sS * 256 + (blockIdx.x * 4 + r)) * 512 + j];
    }
    __syncthreads();
    const float* hrow = hidc[qw];
    #pragma unroll 8
    for (int kk = 0; kk < 128; ++kk)
      acc += hrow[kk] * fcT[(size_t)(k0 + kk) * 64 + o];
    __syncthreads();
  }
  float v = acc + fc_b[o];
  float m = v;
  #pragma unroll
  for (int off = 32; off; off >>= 1) m = fmaxf(m, __shfl_xor(m, off, 64));
  float e = __expf(v - m);
  float ssum = e;
  #pragma unroll
  for (int off = 32; off; off >>= 1) ssum += __shfl_xor(ssum, off, 64);
  out[bi * 64 + o] = e / ssum;
}

// ---------------- launcher ----------------
extern "C" void kernel_launch(void* const* d_in, const int* in_sizes, int n_in,
                              void* d_out, int out_size, void* d_ws, size_t ws_size,
                              hipStream_t stream) {
  const int*   tok   = (const int*)d_in[0];
  const float* embed = (const float*)d_in[1];
  const float* Wih0  = (const float*)d_in[2];
  const float* Whh0  = (const float*)d_in[3];
  const float* bih0  = (const float*)d_in[4];
  const float* bhh0  = (const float*)d_in[5];
  const float* Wih   = (const float*)d_in[6];
  const float* Whh   = (const float*)d_in[7];
  const float* bih   = (const float*)d_in[8];
  const float* bhh   = (const float*)d_in[9];
  const float* fc_w  = (const float*)d_in[10];
  const float* fc_b  = (const float*)d_in[11];
  float* out = (float*)d_out;

  if (ws_size < WS_NEEDED) return;   // fail visibly (poison stays)

  char* ws = (char*)d_ws;
  short* Wfb  = (short*)(ws + OFF_WF);
  float* bsum = (float*)(ws + OFF_BS);
  short* XP   = (short*)(ws + OFF_XP);
  short* hbuf = (short*)(ws + OFF_HB);
  float* cbuf = (float*)(ws + OFF_CB);
  float* hfb  = (float*)(ws + OFF_HF);
  float* fcT  = (float*)(ws + OFF_FC);

  // zero init: h parity-1 half (read as h_{t=-1}) and all of c
  hipMemsetAsync(ws + OFF_HB + N_HBE, 0, N_HBE, stream);          // par1 half (N_HBE/2 shorts *2B)
  hipMemsetAsync(ws + OFF_CB, 0, N_CBE * 4, stream);

  k_prep_wf  <<<(int)((N_WF  + 255) / 256), 256, 0, stream>>>(Wih0, Whh0, Wih, Whh, Wfb);
  k_prep_bias<<<(int)((N_BSE + 255) / 256), 256, 0, stream>>>(bih0, bhh0, bih, bhh, bsum);
  k_prep_xp  <<<(int)((N_XPE + 255) / 256), 256, 0, stream>>>(tok, embed, XP);
  k_prep_fcT <<<(int)((N_FCT + 255) / 256), 256, 0, stream>>>(fc_w, fcT);

  void* kargs[] = {(void*)&Wfb, (void*)&bsum, (void*)&XP,
                   (void*)&hbuf, (void*)&cbuf, (void*)&hfb};
  hipLaunchCooperativeKernel((void*)k_lstm, dim3(256), dim3(512), kargs, 0, stream);

  k_fc<<<64, 256, 0, stream>>>(hfb, cbuf, fcT, fc_b, out);
}

// Round 3
// 6139.192 us; speedup vs baseline: 3.9949x; 1.1339x over previous
//
#include <hip/hip_runtime.h>

using short8 = __attribute__((ext_vector_type(8))) short;
using f32x4  = __attribute__((ext_vector_type(4))) float;
using f32x2  = __attribute__((ext_vector_type(2))) float;

// ---------------- workspace layout ----------------
static constexpr size_t N_WF0 = (size_t)2*32*8*3*4*512;   // shorts
static constexpr size_t N_WF1 = (size_t)6*32*8*6*4*512;   // shorts
static constexpr size_t N_WF  = N_WF0 + N_WF1;
static constexpr size_t N_BSE = (size_t)8*2048;           // f32 bias sums
static constexpr size_t N_XPE = (size_t)128*2*256*8;      // shorts, embed k8-major [t][kg2][b][8]
static constexpr size_t N_HBE = (size_t)2*8*64*256*8;     // shorts, h dbuf [par][ld][kgrp][b][8]
static constexpr size_t N_CBE = (size_t)8*256*512;        // f32 c state [ld][b][j]
static constexpr size_t N_FCT = (size_t)8192*64;          // f32 fc_w^T [k][o]
static constexpr size_t N_FL  = (size_t)8*128;            // int flags [plane][t]

static constexpr size_t OFF_WF = 0;
static constexpr size_t OFF_BS = OFF_WF + N_WF*2;
static constexpr size_t OFF_XP = OFF_BS + N_BSE*4;
static constexpr size_t OFF_HB = OFF_XP + N_XPE*2;
static constexpr size_t OFF_CB = OFF_HB + N_HBE*2;
static constexpr size_t OFF_HF = OFF_CB + N_CBE*4;
static constexpr size_t OFF_FC = OFF_HF + N_CBE*4;
static constexpr size_t OFF_FL = OFF_FC + N_FCT*4;
static constexpr size_t WS_NEEDED = OFF_FL + N_FL*4;

__device__ __forceinline__ short f2bf(float f) {
  unsigned u = __float_as_uint(f);
  u += 0x7fff + ((u >> 16) & 1);   // RNE
  return (short)(u >> 16);
}

__device__ __forceinline__ void wait_ge(int* f, int target) {
  while (__hip_atomic_load(f, __ATOMIC_RELAXED, __HIP_MEMORY_SCOPE_AGENT) < target)
    __builtin_amdgcn_s_sleep(2);
}

// ---------------- prep kernels ----------------
__global__ void k_prep_wf(const float* __restrict__ Wih0, const float* __restrict__ Whh0,
                          const float* __restrict__ Wih,  const float* __restrict__ Whh,
                          short* __restrict__ Wf) {
  size_t idx = (size_t)blockIdx.x * blockDim.x + threadIdx.x;
  if (idx >= N_WF) return;
  int j  = (int)(idx & 7);
  int lane = (int)((idx >> 3) & 63);
  int gt = (int)((idx >> 9) & 3);
  int lr = lane & 15, qq = lane >> 4;
  float v;
  if (idx < N_WF0) {
    size_t rest = idx >> 11;
    int sl = (int)(rest % 3); size_t r2 = rest / 3;
    int wvv = (int)(r2 & 7);  size_t r3 = r2 >> 3;
    int ncc = (int)(r3 & 31); int dd = (int)(r3 >> 5);
    int g = gt*512 + ncc*16 + lr;
    int k = (wvv*3 + sl)*32 + qq*8 + j;           // 0..767
    if (k < 16)       v = Wih0[((size_t)dd*2048 + g)*16 + k];
    else if (k < 64)  v = 0.f;
    else if (k < 576) v = Whh0[((size_t)dd*2048 + g)*512 + (k - 64)];
    else              v = 0.f;
  } else {
    size_t u = idx - N_WF0;
    size_t rest = u >> 11;
    int sl = (int)(rest % 6); size_t r2 = rest / 6;
    int wvv = (int)(r2 & 7);  size_t r3 = r2 >> 3;
    int ncc = (int)(r3 & 31); int ldm = (int)(r3 >> 5);   // (l-1)*2+d
    int g = gt*512 + ncc*16 + lr;
    int k = (wvv*6 + sl)*32 + qq*8 + j;           // 0..1535
    if (k < 1024) v = Wih[((size_t)ldm*2048 + g)*1024 + k];
    else          v = Whh[((size_t)ldm*2048 + g)*512 + (k - 1024)];
  }
  Wf[idx] = f2bf(v);
}

__global__ void k_prep_bias(const float* __restrict__ bih0, const float* __restrict__ bhh0,
                            const float* __restrict__ bih, const float* __restrict__ bhh,
                            float* __restrict__ bsum) {
  int idx = blockIdx.x * blockDim.x + threadIdx.x;
  if (idx >= (int)N_BSE) return;
  int g = idx & 2047;
  int dd = (idx >> 11) & 1;
  int ll = idx >> 12;
  float v;
  if (ll == 0) v = bih0[dd*2048 + g] + bhh0[dd*2048 + g];
  else         v = bih[((ll-1)*2 + dd)*2048 + g] + bhh[((ll-1)*2 + dd)*2048 + g];
  bsum[idx] = v;
}

__global__ void k_prep_xp(const int* __restrict__ tok, const float* __restrict__ embed,
                          short* __restrict__ XP) {
  int idx = blockIdx.x * blockDim.x + threadIdx.x;
  if (idx >= (int)N_XPE) return;
  int i  = idx & 7;
  int b  = (idx >> 3) & 255;
  int kg = (idx >> 11) & 1;
  int t  = idx >> 12;
  int k = kg*8 + i;                                // 0..15
  XP[idx] = f2bf(embed[tok[t*256 + b]*16 + k]);
}

__global__ void k_prep_fcT(const float* __restrict__ fc_w, float* __restrict__ fcT) {
  int idx = blockIdx.x * blockDim.x + threadIdx.x;
  if (idx >= (int)N_FCT) return;
  int o = idx & 63;
  int k = idx >> 6;
  fcT[idx] = fc_w[o * 8192 + k];
}

// ---------------- main recurrent kernel ----------------
// 256 blocks x 512 threads (cooperative launch for co-residency only).
// block = (ld = blk&7, nc = blk>>3); blk&7 also aligns each plane to one XCD
// (round-robin block->XCD dispatch), keeping self-plane h/c traffic XCD-local.
// NO grid barrier: per-(plane,t) ready flags; block loops t = 0..127 directly.
// Deps of (l,t): (l,t-1) self, (l-1,t) inputs, (l+1,t-2) back-pressure
// (h is parity-double-buffered). All deps have smaller t+l -> DAG, no deadlock.
__global__ void __launch_bounds__(512, 2)
k_lstm(const short* __restrict__ Wf, const float* __restrict__ bsum,
       const short* __restrict__ XP, short* __restrict__ hb,
       float* __restrict__ cb, float* __restrict__ hf, int* __restrict__ Fl) {
  const int blk = blockIdx.x;
  const int ld = blk & 7, nc = blk >> 3;
  const int l = ld >> 1, d = ld & 1;
  const int tid = threadIdx.x;
  const int wv = tid >> 6, lane = tid & 63;
  const int q = lane >> 4, lr = lane & 15;
  const int SLb = (l == 0) ? 3 : 6;
  const size_t HB_LD = 131072;   // shorts per (par,ld) h-buffer

  __shared__ float red[2][8][4][16][16];   // [mt][wv][gt][n][m] = 64 KB

  const int eu  = tid >> 7;        // mt within pair
  const int en  = (tid >> 3) & 15; // n col
  const int emh = tid & 7;         // m half-quad
  float bias4[4];
  if (tid < 256) {
    #pragma unroll
    for (int gt = 0; gt < 4; ++gt)
      bias4[gt] = bsum[ld*2048 + gt*512 + nc*16 + en];
  }

  // ---- persistent weight registers (96 VGPR/lane) ----
  short8 wreg[6][4];
  {
    const short* wb = (l == 0)
      ? (Wf + (size_t)(d*32 + nc) * (8*3*4*512) + (size_t)wv * (3*4*512))
      : (Wf + N_WF0 + (size_t)((ld - 2)*32 + nc) * (8*6*4*512) + (size_t)wv * (6*4*512));
    #pragma unroll
    for (int sl = 0; sl < 6; ++sl) {
      #pragma unroll
      for (int gt = 0; gt < 4; ++gt) {
        if (sl < SLb) wreg[sl][gt] = *(const short8*)(wb + (sl*4 + gt)*512 + lane*8);
        else          wreg[sl][gt] = short8{0,0,0,0,0,0,0,0};
      }
    }
  }

  float* cbl = cb + (size_t)ld * (256*512);

  for (int t = 0; t < 128; ++t) {
    // ---- fine-grained waits (thread 0 spins, relaxed polls) ----
    if (tid == 0) {
      if (t > 0) wait_ge(Fl + ld*128 + (t-1), 32);          // self-recurrence
      if (l > 0) {                                           // prev-layer h at t
        wait_ge(Fl + (ld-2-d)*128 + t, 32);
        wait_ge(Fl + (ld-1-d)*128 + t, 32);
      }
      if (l < 3 && t >= 2) {                                 // back-pressure (h dbuf)
        wait_ge(Fl + (2*l+2)*128 + (t-2), 32);
        wait_ge(Fl + (2*l+3)*128 + (t-2), 32);
      }
    }
    __syncthreads();
    __builtin_amdgcn_fence(__ATOMIC_ACQUIRE, "agent");       // invalidate stale L1/L2

    const int pt = t & 1, pm = pt ^ 1;
    // per-slab lane-adjusted A pointers (k8-major sources)
    const short* apl[6];
    #pragma unroll
    for (int sl = 0; sl < 6; ++sl) {
      int S = wv * SLb + sl;
      const short* p; int lo;
      if (l == 0) {
        if (S < 2) { p = XP + (size_t)t * 4096; lo = (q < 1 ? q : 1) * 2048 + lr * 8; }
        else {
          int klb = (S <= 17) ? (4*S - 8) : 0;   // S>17: zero weights, any valid addr
          p = hb + (size_t)(pm*8 + ld) * HB_LD + (size_t)klb * 2048;
          lo = q * 2048 + lr * 8;
        }
      } else {
        const int pl0 = ld - 2 - d;              // (l-1)*2
        if (S < 16)      p = hb + (size_t)(pt*8 + pl0    ) * HB_LD + (size_t)(4*S      ) * 2048;
        else if (S < 32) p = hb + (size_t)(pt*8 + pl0 + 1) * HB_LD + (size_t)(4*S - 64 ) * 2048;
        else             p = hb + (size_t)(pm*8 + ld     ) * HB_LD + (size_t)(4*S - 128) * 2048;
        lo = q * 2048 + lr * 8;
      }
      apl[sl] = p + lo;
    }

    // prime A for round 0
    short8 a[6][2];
    #pragma unroll
    for (int sl = 0; sl < 6; ++sl)
      if (sl < SLb) {
        a[sl][0] = *(const short8*)(apl[sl]);
        a[sl][1] = *(const short8*)(apl[sl] + 128);
      }

    for (int ro = 0; ro < 8; ++ro) {   // 8 rounds x 2 m-tiles = 256 batch rows
      float c0 = 0.f, c1 = 0.f; int b0 = 0, b1 = 0, ej = 0;
      if (tid < 256) {
        ej = nc*16 + en;
        b0 = (ro*2 + eu)*16 + emh*2;
        b1 = b0 + 1;
        c0 = cbl[(size_t)b0*512 + ej];
        c1 = cbl[(size_t)b1*512 + ej];
      }
      f32x4 acc[2][4];
      #pragma unroll
      for (int u = 0; u < 2; ++u)
        #pragma unroll
        for (int gt = 0; gt < 4; ++gt) acc[u][gt] = f32x4{0.f,0.f,0.f,0.f};
      #pragma unroll
      for (int sl = 0; sl < 6; ++sl)
        if (sl < SLb) {
          #pragma unroll
          for (int gt = 0; gt < 4; ++gt) {
            acc[0][gt] = __builtin_amdgcn_mfma_f32_16x16x32_bf16(a[sl][0], wreg[sl][gt], acc[0][gt], 0,0,0);
            acc[1][gt] = __builtin_amdgcn_mfma_f32_16x16x32_bf16(a[sl][1], wreg[sl][gt], acc[1][gt], 0,0,0);
          }
        }
      if (ro < 7) {
        const int mo = (ro + 1) * 256;
        #pragma unroll
        for (int sl = 0; sl < 6; ++sl)
          if (sl < SLb) {
            a[sl][0] = *(const short8*)(apl[sl] + mo);
            a[sl][1] = *(const short8*)(apl[sl] + mo + 128);
          }
      }
      #pragma unroll
      for (int u = 0; u < 2; ++u)
        #pragma unroll
        for (int gt = 0; gt < 4; ++gt)
          *(f32x4*)&red[u][wv][gt][lr][q*4] = acc[u][gt];
      __syncthreads();
      if (tid < 256) {
        float g2[4][2];
        #pragma unroll
        for (int gt = 0; gt < 4; ++gt) {
          f32x2 sum = f32x2{0.f, 0.f};
          #pragma unroll
          for (int w8 = 0; w8 < 8; ++w8)
            sum += *(const f32x2*)&red[eu][w8][gt][en][emh*2];
          g2[gt][0] = sum[0] + bias4[gt];
          g2[gt][1] = sum[1] + bias4[gt];
        }
        short* hw = hb + (size_t)(pt*8 + ld) * HB_LD;
        #pragma unroll
        for (int e = 0; e < 2; ++e) {
          float gi = g2[0][e], gf = g2[1][e], gg = g2[2][e], go = g2[3][e];
          float si = 1.f/(1.f + __expf(-gi));
          float sf = 1.f/(1.f + __expf(-gf));
          float so = 1.f/(1.f + __expf(-go));
          float tg = 1.f - 2.f/(1.f + __expf(2.f*gg));
          float cold = e ? c1 : c0;
          int   b    = e ? b1 : b0;
          float cn = sf * cold + si * tg;
          float tc = 1.f - 2.f/(1.f + __expf(2.f*cn));
          float hn = so * tc;
          cbl[(size_t)b*512 + ej] = cn;
          hw[((size_t)(ej >> 3) * 256 + b) * 8 + (ej & 7)] = f2bf(hn);
          if (t == 127) hf[((size_t)ld*256 + b)*512 + ej] = hn;
        }
      }
      __syncthreads();
    }

    // ---- signal: this block's j-slice of h[ld][t] is globally visible ----
    if (tid == 0)
      __hip_atomic_fetch_add(Fl + ld*128 + t, 1, __ATOMIC_RELEASE, __HIP_MEMORY_SCOPE_AGENT);
  }
}

// ---------------- final FC + softmax ----------------
__global__ void __launch_bounds__(256)
k_fc(const float* __restrict__ hf, const float* __restrict__ cb,
     const float* __restrict__ fcT, const float* __restrict__ fc_b,
     float* __restrict__ out) {
  const int tid = threadIdx.x;
  const int o = tid & 63;
  const int qw = tid >> 6;
  const int bi = blockIdx.x * 4 + qw;
  __shared__ float hidc[4][128];
  float acc = 0.f;
  for (int k0 = 0; k0 < 8192; k0 += 128) {
    #pragma unroll
    for (int c = 0; c < 2; ++c) {
      int idx = tid + c * 256;                 // 0..511
      int r = idx >> 7, kk = idx & 127;
      int k = k0 + kk;
      int sS = k >> 10, rem = k & 1023, part = rem >> 9, j = rem & 511;
      const float* src = part ? cb : hf;       // hid = [h | c] per (l,d) slice
      hidc[r][kk] = src[((size_t)sS * 256 + (blockIdx.x * 4 + r)) * 512 + j];
    }
    __syncthreads();
    const float* hrow = hidc[qw];
    #pragma unroll 8
    for (int kk = 0; kk < 128; ++kk)
      acc += hrow[kk] * fcT[(size_t)(k0 + kk) * 64 + o];
    __syncthreads();
  }
  float v = acc + fc_b[o];
  float m = v;
  #pragma unroll
  for (int off = 32; off; off >>= 1) m = fmaxf(m, __shfl_xor(m, off, 64));
  float e = __expf(v - m);
  float ssum = e;
  #pragma unroll
  for (int off = 32; off; off >>= 1) ssum += __shfl_xor(ssum, off, 64);
  out[bi * 64 + o] = e / ssum;
}

// ---------------- launcher ----------------
extern "C" void kernel_launch(void* const* d_in, const int* in_sizes, int n_in,
                              void* d_out, int out_size, void* d_ws, size_t ws_size,
                              hipStream_t stream) {
  const int*   tok   = (const int*)d_in[0];
  const float* embed = (const float*)d_in[1];
  const float* Wih0  = (const float*)d_in[2];
  const float* Whh0  = (const float*)d_in[3];
  const float* bih0  = (const float*)d_in[4];
  const float* bhh0  = (const float*)d_in[5];
  const float* Wih   = (const float*)d_in[6];
  const float* Whh   = (const float*)d_in[7];
  const float* bih   = (const float*)d_in[8];
  const float* bhh   = (const float*)d_in[9];
  const float* fc_w  = (const float*)d_in[10];
  const float* fc_b  = (const float*)d_in[11];
  float* out = (float*)d_out;

  if (ws_size < WS_NEEDED) return;   // fail visibly (poison stays)

  char* ws = (char*)d_ws;
  short* Wfb  = (short*)(ws + OFF_WF);
  float* bsum = (float*)(ws + OFF_BS);
  short* XP   = (short*)(ws + OFF_XP);
  short* hbuf = (short*)(ws + OFF_HB);
  float* cbuf = (float*)(ws + OFF_CB);
  float* hfb  = (float*)(ws + OFF_HF);
  float* fcT  = (float*)(ws + OFF_FC);
  int*   flg  = (int*)  (ws + OFF_FL);

  // zero init: h parity-1 half (read as h_{t=-1}), all of c, and the flags
  hipMemsetAsync(ws + OFF_HB + N_HBE, 0, N_HBE, stream);
  hipMemsetAsync(ws + OFF_CB, 0, N_CBE * 4, stream);
  hipMemsetAsync(ws + OFF_FL, 0, N_FL * 4, stream);

  k_prep_wf  <<<(int)((N_WF  + 255) / 256), 256, 0, stream>>>(Wih0, Whh0, Wih, Whh, Wfb);
  k_prep_bias<<<(int)((N_BSE + 255) / 256), 256, 0, stream>>>(bih0, bhh0, bih, bhh, bsum);
  k_prep_xp  <<<(int)((N_XPE + 255) / 256), 256, 0, stream>>>(tok, embed, XP);
  k_prep_fcT <<<(int)((N_FCT + 255) / 256), 256, 0, stream>>>(fc_w, fcT);

  void* kargs[] = {(void*)&Wfb, (void*)&bsum, (void*)&XP,
                   (void*)&hbuf, (void*)&cbuf, (void*)&hfb, (void*)&flg};
  hipLaunchCooperativeKernel((void*)k_lstm, dim3(256), dim3(512), kargs, 0, stream);

  k_fc<<<64, 256, 0, stream>>>(hfb, cbuf, fcT, fc_b, out);
}